// Round 11
// baseline (58.792 us; speedup 1.0000x reference)
//
#include <hip/hip_runtime.h>

#define NFEAS 4096
#define HID   128
#define BATCH 128
#define NSUB  64          // T granularity: 64 sub-chunks of 64 features
#define NCH   16          // scan chunks of KF features
#define KF    256
#define L2E   1.4426950408889634f
#define LN2   0.6931471805599453f

// 64-lane inclusive prefix sum — fused v_add_f32_dpp (1 instr/step vs 3 for
// update_dpp+add). Single-chain version: s_nop 1 between steps satisfies the
// 2-wait-state VALU-write -> DPP-read hazard (software-enforced on gfx9+).
__device__ __forceinline__ float scan64(float v) {
  float r = v;
  asm volatile(
    "s_nop 1\n\t"
    "v_add_f32_dpp %0, %0, %0 row_shr:1 row_mask:0xf bank_mask:0xf bound_ctrl:0\n\t"
    "s_nop 1\n\t"
    "v_add_f32_dpp %0, %0, %0 row_shr:2 row_mask:0xf bank_mask:0xf bound_ctrl:0\n\t"
    "s_nop 1\n\t"
    "v_add_f32_dpp %0, %0, %0 row_shr:4 row_mask:0xf bank_mask:0xf bound_ctrl:0\n\t"
    "s_nop 1\n\t"
    "v_add_f32_dpp %0, %0, %0 row_shr:8 row_mask:0xf bank_mask:0xf bound_ctrl:0\n\t"
    "s_nop 1\n\t"
    "v_add_f32_dpp %0, %0, %0 row_bcast:15 row_mask:0xa bank_mask:0xf bound_ctrl:0\n\t"
    "s_nop 1\n\t"
    "v_add_f32_dpp %0, %0, %0 row_bcast:31 row_mask:0xc bank_mask:0xf bound_ctrl:0"
    : "+v"(r));
  return r;
}

// Four independent scans, steps interleaved: 3 instructions between dependent
// steps of the same chain -> hazard satisfied without nops (one at entry for
// the freshly-computed inputs).
__device__ __forceinline__ void scan64_x4(float& a, float& b, float& c, float& d) {
#define STEP4(mod)                                  \
    "v_add_f32_dpp %0, %0, %0 " mod "\n\t"          \
    "v_add_f32_dpp %1, %1, %1 " mod "\n\t"          \
    "v_add_f32_dpp %2, %2, %2 " mod "\n\t"          \
    "v_add_f32_dpp %3, %3, %3 " mod "\n\t"
  asm volatile(
    "s_nop 1\n\t"
    STEP4("row_shr:1 row_mask:0xf bank_mask:0xf bound_ctrl:0")
    STEP4("row_shr:2 row_mask:0xf bank_mask:0xf bound_ctrl:0")
    STEP4("row_shr:4 row_mask:0xf bank_mask:0xf bound_ctrl:0")
    STEP4("row_shr:8 row_mask:0xf bank_mask:0xf bound_ctrl:0")
    STEP4("row_bcast:15 row_mask:0xa bank_mask:0xf bound_ctrl:0")
    "v_add_f32_dpp %0, %0, %0 row_bcast:31 row_mask:0xc bank_mask:0xf bound_ctrl:0\n\t"
    "v_add_f32_dpp %1, %1, %1 row_bcast:31 row_mask:0xc bank_mask:0xf bound_ctrl:0\n\t"
    "v_add_f32_dpp %2, %2, %2 row_bcast:31 row_mask:0xc bank_mask:0xf bound_ctrl:0\n\t"
    "v_add_f32_dpp %3, %3, %3 row_bcast:31 row_mask:0xc bank_mask:0xf bound_ctrl:0"
    : "+v"(a), "+v"(b), "+v"(c), "+v"(d));
#undef STEP4
}

// ---------------------------------------------------------------------------
// Phase A: T[b][h][c] = sum_{f in 64-subchunk c} (x[b,f]>0) * W[f,h]
// Block = (subchunk c, 8-sample group): W row read once per 8 samples.
// ---------------------------------------------------------------------------
__global__ __launch_bounds__(128) void chunk_sums_kernel(
    const float* __restrict__ x, const float* __restrict__ W,
    float* __restrict__ T)
{
  __shared__ float xm[64][8];    // xm[f][s]
  const int c = blockIdx.x, g = blockIdx.y, t = threadIdx.x;

  { // stage x>0 masks for 8 samples x 64 features
    const int s = t >> 4, fb = (t & 15) << 2;
    const float4 v = *reinterpret_cast<const float4*>(
        &x[(size_t)(g * 8 + s) * NFEAS + c * 64 + fb]);
    xm[fb + 0][s] = v.x > 0.f ? 1.f : 0.f;
    xm[fb + 1][s] = v.y > 0.f ? 1.f : 0.f;
    xm[fb + 2][s] = v.z > 0.f ? 1.f : 0.f;
    xm[fb + 3][s] = v.w > 0.f ? 1.f : 0.f;
  }
  __syncthreads();

  float acc[8];
  #pragma unroll
  for (int s = 0; s < 8; ++s) acc[s] = 0.f;

  #pragma unroll 4
  for (int f = 0; f < 64; ++f) {
    const float wv = W[(size_t)(c * 64 + f) * HID + t];   // coalesced
    const float4 ma = *reinterpret_cast<const float4*>(&xm[f][0]);  // broadcast
    const float4 mb = *reinterpret_cast<const float4*>(&xm[f][4]);
    acc[0] = __builtin_fmaf(ma.x, wv, acc[0]);
    acc[1] = __builtin_fmaf(ma.y, wv, acc[1]);
    acc[2] = __builtin_fmaf(ma.z, wv, acc[2]);
    acc[3] = __builtin_fmaf(ma.w, wv, acc[3]);
    acc[4] = __builtin_fmaf(mb.x, wv, acc[4]);
    acc[5] = __builtin_fmaf(mb.y, wv, acc[5]);
    acc[6] = __builtin_fmaf(mb.z, wv, acc[6]);
    acc[7] = __builtin_fmaf(mb.w, wv, acc[7]);
  }
  #pragma unroll
  for (int s = 0; s < 8; ++s)
    T[((size_t)(g * 8 + s) * HID + t) * NSUB + c] = acc[s];
}

// ---------------------------------------------------------------------------
// Phase B: scan T[b][h][0..63] (one wave per (b,h)) and emit the per-chunk
// sigmoid pre-arg table s2m[c][b][h] = -log2e * (prefix_at_chunk_c + C[h]).
// ---------------------------------------------------------------------------
__global__ __launch_bounds__(256) void prefix_s2m_kernel(
    const float* __restrict__ T, const float* __restrict__ Cv,
    float* __restrict__ s2m)
{
  const int gw = blockIdx.x * 4 + (threadIdx.x >> 6);  // b*128 + h
  const int lane = threadIdx.x & 63;
  const int h = gw & 127;
  const float v = T[(size_t)gw * NSUB + lane];
  const float r = scan64(v);
  if ((lane & 3) == 0) {                               // lane = 4c
    const float excl = r - v;                          // prefix before chunk c
    s2m[(size_t)(lane >> 2) * (BATCH * HID) + gw] = -L2E * (excl + Cv[h]);
  }
}

// ---------------------------------------------------------------------------
// Phase C: zpart[hq][b][f] = sum_{h in quarter hq} sigmoid(S_excl+C) * W[f,h]
// Block = (chunk c, h-quarter hq, 8-sample group). W slice staged ONCE;
// each wave owns one sample and sweeps all 32 h chains — no barriers, no
// VMEM in the main loop. DPP scans 4-way interleaved (fused asm).
// ---------------------------------------------------------------------------
__global__ __launch_bounds__(512, 6) void zpart_kernel(
    const float* __restrict__ x,   const float* __restrict__ W,
    const float* __restrict__ Cv,  const float* __restrict__ s2m,
    float* __restrict__ zpart)
{
  __shared__ float wt[32 * 256];   // wt[ch][f ^ ((ch>>2&3)<<3)]
  __shared__ float s2l[8 * 32];    // [sample-in-block][ch]
  __shared__ float cvl[32];        // C slice (raw-C quirk at global f==0)

  const int c  = blockIdx.x;       // 0..15
  const int hq = blockIdx.y;       // 0..3
  const int bg = blockIdx.z;       // 0..15
  const int tid = threadIdx.x, lane = tid & 63, w = tid >> 6;
  const int base = c * KF;

  { // stage W slice [32h x 256f], coalesced along h, XOR-swizzled columns
    const int hb = tid & 7, f0 = tid >> 3;          // f0: 0..63
    const float* wp = W + (size_t)(base + f0) * HID + (hq << 5) + (hb << 2);
    const int colw = f0 ^ ((hb & 3) << 3);
    #pragma unroll
    for (int k = 0; k < 4; ++k) {
      const float4 v = *reinterpret_cast<const float4*>(wp + (size_t)(k << 6) * HID);
      float* q = &wt[((hb << 2) << 8) + colw + (k << 6)];
      q[0] = v.x; q[256] = v.y; q[512] = v.z; q[768] = v.w;
    }
  }
  if (tid < 256) {                 // s = tid>>5 (sample), ch = tid&31
    s2l[tid] = s2m[(size_t)c * (BATCH * HID) +
                   (size_t)(bg * 8 + (tid >> 5)) * HID + (hq << 5) + (tid & 31)];
  }
  if (tid < 32) cvl[tid] = Cv[(hq << 5) + tid];
  __syncthreads();

  const int b = bg * 8 + w;        // wave's sample
  const float4 xv = *reinterpret_cast<const float4*>(
      x + (size_t)b * NFEAS + base + (lane << 2));
  const float xm0 = xv.x > 0.f ? 1.f : 0.f;
  const float xm1 = xv.y > 0.f ? 1.f : 0.f;
  const float xm2 = xv.z > 0.f ? 1.f : 0.f;
  const float xm3 = xv.w > 0.f ? 1.f : 0.f;
  const bool qk = (c == 0) && (lane == 0);

  float z0 = 0.f, z1 = 0.f, z2 = 0.f, z3 = 0.f;
  const float* s2p = &s2l[w << 5];

  #pragma unroll
  for (int cg = 0; cg < 8; ++cg) {           // chains ch = 4*cg .. 4*cg+3
    const int colx = (lane << 2) ^ ((cg & 3) << 3);
    const int rb = (cg << 2) * 256 + colx;
    const float4 wv0 = *reinterpret_cast<const float4*>(&wt[rb]);
    const float4 wv1 = *reinterpret_cast<const float4*>(&wt[rb + 256]);
    const float4 wv2 = *reinterpret_cast<const float4*>(&wt[rb + 512]);
    const float4 wv3 = *reinterpret_cast<const float4*>(&wt[rb + 768]);

    const float m00 = wv0.x * xm0, m01 = wv0.y * xm1, m02 = wv0.z * xm2;
    const float m10 = wv1.x * xm0, m11 = wv1.y * xm1, m12 = wv1.z * xm2;
    const float m20 = wv2.x * xm0, m21 = wv2.y * xm1, m22 = wv2.z * xm2;
    const float m30 = wv3.x * xm0, m31 = wv3.y * xm1, m32 = wv3.z * xm2;

    const float ps0 = (m00 + m01) + (m02 + wv0.w * xm3);
    const float ps1 = (m10 + m11) + (m12 + wv1.w * xm3);
    const float ps2 = (m20 + m21) + (m22 + wv2.w * xm3);
    const float ps3 = (m30 + m31) + (m32 + wv3.w * xm3);

    float r0 = ps0, r1 = ps1, r2 = ps2, r3 = ps3;
    scan64_x4(r0, r1, r2, r3);

#define CHAIN(J, wvJ, rJ, psJ, mJ0, mJ1, mJ2)                                               \
    {                                                                                        \
      const int ch = (cg << 2) + J;                                                          \
      const float smv = s2p[ch];                                                             \
      const float e0 = rJ - psJ;                                                             \
      const float e1 = e0 + mJ0;                                                             \
      const float e2 = e1 + mJ1;                                                             \
      const float e3 = e2 + mJ2;                                                             \
      float g0 = __builtin_amdgcn_rcpf(1.f + __builtin_amdgcn_exp2f(__builtin_fmaf(e0, -L2E, smv))); \
      const float g1 = __builtin_amdgcn_rcpf(1.f + __builtin_amdgcn_exp2f(__builtin_fmaf(e1, -L2E, smv))); \
      const float g2 = __builtin_amdgcn_rcpf(1.f + __builtin_amdgcn_exp2f(__builtin_fmaf(e2, -L2E, smv))); \
      const float g3 = __builtin_amdgcn_rcpf(1.f + __builtin_amdgcn_exp2f(__builtin_fmaf(e3, -L2E, smv))); \
      if (qk) g0 = cvl[ch];                    /* raw C at global feature 0 */               \
      z0 = __builtin_fmaf(g0, wvJ.x, z0);                                                    \
      z1 = __builtin_fmaf(g1, wvJ.y, z1);                                                    \
      z2 = __builtin_fmaf(g2, wvJ.z, z2);                                                    \
      z3 = __builtin_fmaf(g3, wvJ.w, z3);                                                    \
    }
    CHAIN(0, wv0, r0, ps0, m00, m01, m02)
    CHAIN(1, wv1, r1, ps1, m10, m11, m12)
    CHAIN(2, wv2, r2, ps2, m20, m21, m22)
    CHAIN(3, wv3, r3, ps3, m30, m31, m32)
#undef CHAIN
  }

  float4 zv; zv.x = z0; zv.y = z1; zv.z = z2; zv.w = z3;
  *reinterpret_cast<float4*>(
      &zpart[((size_t)hq * BATCH + b) * NFEAS + base + (lane << 2)]) = zv;
}

// ---------------------------------------------------------------------------
// Phase D: per-(sample, f-quarter) BCE over z = sum_hq zpart + B.
// Grid (BATCH, 4) = 512 blocks -> whole machine busy, float4 loads.
// ---------------------------------------------------------------------------
__global__ __launch_bounds__(256) void bce_kernel(
    const float* __restrict__ x, const float* __restrict__ Bv,
    const float* __restrict__ zpart, float* __restrict__ lossb)
{
  __shared__ float sm[256];
  const int b = blockIdx.x, q = blockIdx.y, t = threadIdx.x;
  const int fb = (q << 10) + (t << 2);          // 4 consecutive features
  const size_t Q = (size_t)BATCH * NFEAS;
  const size_t o = (size_t)b * NFEAS + fb;

  float4 zt = *reinterpret_cast<const float4*>(&zpart[o]);
  #pragma unroll
  for (int s = 1; s < 4; ++s) {
    const float4 v = *reinterpret_cast<const float4*>(&zpart[(size_t)s * Q + o]);
    zt.x += v.x; zt.y += v.y; zt.z += v.z; zt.w += v.w;
  }
  const float4 bv = *reinterpret_cast<const float4*>(Bv + fb);
  zt.x += bv.x; zt.y += bv.y; zt.z += bv.z; zt.w += bv.w;
  const float4 xv = *reinterpret_cast<const float4*>(&x[o]);

#define BCE(zv, xvv)                                                      \
  (fmaxf(zv, 0.f) - ((xvv) > 0.f ? (zv) : 0.f) +                          \
   LN2 * __builtin_amdgcn_logf(1.f + __builtin_amdgcn_exp2f(-L2E * __builtin_fabsf(zv))))
  const float li = (BCE(zt.x, xv.x) + BCE(zt.y, xv.y)) +
                   (BCE(zt.z, xv.z) + BCE(zt.w, xv.w));
#undef BCE

  sm[t] = li;
  __syncthreads();
  for (int s = 128; s > 0; s >>= 1) {
    if (t < s) sm[t] += sm[t + s];
    __syncthreads();
  }
  if (t == 0) lossb[b * 4 + q] = sm[0];
}

// ---------------------------------------------------------------------------
// Finalize: mean over the 512 partial losses.
// ---------------------------------------------------------------------------
__global__ __launch_bounds__(256) void finalize_kernel(
    const float* __restrict__ lossb, float* __restrict__ out)
{
  __shared__ float sm[256];
  const int t = threadIdx.x;
  sm[t] = lossb[t] + lossb[t + 256];
  __syncthreads();
  for (int s = 128; s > 0; s >>= 1) {
    if (t < s) sm[t] += sm[t + s];
    __syncthreads();
  }
  if (t == 0) out[0] = sm[0] * (1.f / BATCH);
}

// ---------------------------------------------------------------------------
extern "C" void kernel_launch(void* const* d_in, const int* in_sizes, int n_in,
                              void* d_out, int out_size, void* d_ws, size_t ws_size,
                              hipStream_t stream)
{
  const float* x  = (const float*)d_in[0];  // [BATCH, NFEAS]
  const float* Cv = (const float*)d_in[1];  // [1, HID]
  const float* W  = (const float*)d_in[2];  // [NFEAS, HID]
  const float* Bv = (const float*)d_in[3];  // [NFEAS]
  float* out = (float*)d_out;

  float* T     = (float*)d_ws;                         // [B][HID][64]   4 MB
  float* s2m   = T     + (size_t)BATCH * HID * NSUB;   // [16][B][HID]   1 MB
  float* zpart = s2m   + (size_t)NCH * BATCH * HID;    // [4][B][NFEAS]  8 MB
  float* lossb = zpart + (size_t)4 * BATCH * NFEAS;    // [B*4]

  chunk_sums_kernel<<<dim3(NSUB, BATCH / 8), 128, 0, stream>>>(x, W, T);
  prefix_s2m_kernel<<<dim3(BATCH * HID / 4), 256, 0, stream>>>(T, Cv, s2m);
  zpart_kernel<<<dim3(NCH, 4, BATCH / 8), 512, 0, stream>>>(x, W, Cv, s2m, zpart);
  bce_kernel<<<dim3(BATCH, 4), 256, 0, stream>>>(x, Bv, zpart, lossb);
  finalize_kernel<<<1, 256, 0, stream>>>(lossb, out);
}

// Round 13
// 52.387 us; speedup vs baseline: 1.1223x; 1.1223x over previous
//
#include <hip/hip_runtime.h>

#define NFEAS 4096
#define HID   128
#define BATCH 128
#define NSUB  64          // T granularity: 64 sub-chunks of 64 features
#define NCH   16          // scan chunks of KF features
#define KF    256
#define L2E   1.4426950408889634f
#define LN2   0.6931471805599453f

typedef float f32x4 __attribute__((ext_vector_type(4)));   // native vec for NT builtins

// 64-lane inclusive prefix sum (canonical GCN DPP sequence), single chain.
__device__ __forceinline__ float scan64(float v) {
  float r = v; int y;
  y = __builtin_amdgcn_update_dpp(0, __float_as_int(r), 0x111, 0xF, 0xF, true); r += __int_as_float(y);
  y = __builtin_amdgcn_update_dpp(0, __float_as_int(r), 0x112, 0xF, 0xF, true); r += __int_as_float(y);
  y = __builtin_amdgcn_update_dpp(0, __float_as_int(r), 0x114, 0xF, 0xF, true); r += __int_as_float(y);
  y = __builtin_amdgcn_update_dpp(0, __float_as_int(r), 0x118, 0xF, 0xF, true); r += __int_as_float(y);
  y = __builtin_amdgcn_update_dpp(0, __float_as_int(r), 0x142, 0xA, 0xF, true); r += __int_as_float(y);
  y = __builtin_amdgcn_update_dpp(0, __float_as_int(r), 0x143, 0xC, 0xF, true); r += __int_as_float(y);
  return r;
}

// Four independent 64-lane scans, steps interleaved (hides DPP latency).
__device__ __forceinline__ void scan64_x4(float& a, float& b, float& c, float& d) {
  int t0, t1, t2, t3;
#define S4(ctrl, rm)                                                              \
  t0 = __builtin_amdgcn_update_dpp(0, __float_as_int(a), ctrl, rm, 0xF, true);    \
  t1 = __builtin_amdgcn_update_dpp(0, __float_as_int(b), ctrl, rm, 0xF, true);    \
  t2 = __builtin_amdgcn_update_dpp(0, __float_as_int(c), ctrl, rm, 0xF, true);    \
  t3 = __builtin_amdgcn_update_dpp(0, __float_as_int(d), ctrl, rm, 0xF, true);    \
  a += __int_as_float(t0); b += __int_as_float(t1);                               \
  c += __int_as_float(t2); d += __int_as_float(t3);
  S4(0x111, 0xF) S4(0x112, 0xF) S4(0x114, 0xF) S4(0x118, 0xF)
  S4(0x142, 0xA) S4(0x143, 0xC)
#undef S4
}

// ---------------------------------------------------------------------------
// Phase A: T[b][h][c] = sum_{f in 64-subchunk c} (x[b,f]>0) * W[f,h]
// Block = (subchunk c, 8-sample group): W row read once per 8 samples.
// ---------------------------------------------------------------------------
__global__ __launch_bounds__(128) void chunk_sums_kernel(
    const float* __restrict__ x, const float* __restrict__ W,
    float* __restrict__ T)
{
  __shared__ float xm[64][8];    // xm[f][s]
  const int c = blockIdx.x, g = blockIdx.y, t = threadIdx.x;

  { // stage x>0 masks for 8 samples x 64 features
    const int s = t >> 4, fb = (t & 15) << 2;
    const float4 v = *reinterpret_cast<const float4*>(
        &x[(size_t)(g * 8 + s) * NFEAS + c * 64 + fb]);
    xm[fb + 0][s] = v.x > 0.f ? 1.f : 0.f;
    xm[fb + 1][s] = v.y > 0.f ? 1.f : 0.f;
    xm[fb + 2][s] = v.z > 0.f ? 1.f : 0.f;
    xm[fb + 3][s] = v.w > 0.f ? 1.f : 0.f;
  }
  __syncthreads();

  float acc[8];
  #pragma unroll
  for (int s = 0; s < 8; ++s) acc[s] = 0.f;

  #pragma unroll 4
  for (int f = 0; f < 64; ++f) {
    const float wv = W[(size_t)(c * 64 + f) * HID + t];   // coalesced
    const float4 ma = *reinterpret_cast<const float4*>(&xm[f][0]);  // broadcast
    const float4 mb = *reinterpret_cast<const float4*>(&xm[f][4]);
    acc[0] = __builtin_fmaf(ma.x, wv, acc[0]);
    acc[1] = __builtin_fmaf(ma.y, wv, acc[1]);
    acc[2] = __builtin_fmaf(ma.z, wv, acc[2]);
    acc[3] = __builtin_fmaf(ma.w, wv, acc[3]);
    acc[4] = __builtin_fmaf(mb.x, wv, acc[4]);
    acc[5] = __builtin_fmaf(mb.y, wv, acc[5]);
    acc[6] = __builtin_fmaf(mb.z, wv, acc[6]);
    acc[7] = __builtin_fmaf(mb.w, wv, acc[7]);
  }
  #pragma unroll
  for (int s = 0; s < 8; ++s)
    T[((size_t)(g * 8 + s) * HID + t) * NSUB + c] = acc[s];
}

// ---------------------------------------------------------------------------
// Phase B: scan T[b][h][0..63] (one wave per (b,h)) and emit the per-chunk
// sigmoid pre-arg table s2m[c][b][h] = -log2e * (prefix_at_chunk_c + C[h]).
// ---------------------------------------------------------------------------
__global__ __launch_bounds__(256) void prefix_s2m_kernel(
    const float* __restrict__ T, const float* __restrict__ Cv,
    float* __restrict__ s2m)
{
  const int gw = blockIdx.x * 4 + (threadIdx.x >> 6);  // b*128 + h
  const int lane = threadIdx.x & 63;
  const int h = gw & 127;
  const float v = T[(size_t)gw * NSUB + lane];
  const float r = scan64(v);
  if ((lane & 3) == 0) {                               // lane = 4c
    const float excl = r - v;                          // prefix before chunk c
    s2m[(size_t)(lane >> 2) * (BATCH * HID) + gw] = -L2E * (excl + Cv[h]);
  }
}

// ---------------------------------------------------------------------------
// Phase C: zpart[hq][b][f] = sum_{h in quarter hq} sigmoid(S_excl+C) * W[f,h]
// Block = (8-sample group bg [FAST axis], chunk c, h-quarter hq): consecutive
// blocks share the same 32KB W slice -> L2/L3 coalesced staging.
// zpart stores are non-temporal (don't evict W from L2).
// ---------------------------------------------------------------------------
__global__ __launch_bounds__(512, 6) void zpart_kernel(
    const float* __restrict__ x,   const float* __restrict__ W,
    const float* __restrict__ Cv,  const float* __restrict__ s2m,
    float* __restrict__ zpart)
{
  __shared__ float wt[32 * 256];   // wt[ch][f ^ ((ch>>2&3)<<3)]
  __shared__ float s2l[8 * 32];    // [sample-in-block][ch]
  __shared__ float cvl[32];        // C slice (raw-C quirk at global f==0)

  const int bg = blockIdx.x;       // 0..15  (fast axis: shares W slice)
  const int c  = blockIdx.y;       // 0..15
  const int hq = blockIdx.z;       // 0..3
  const int tid = threadIdx.x, lane = tid & 63, w = tid >> 6;
  const int base = c * KF;

  // hoisted per-wave loads: issue BEFORE staging so latency overlaps
  const int b = bg * 8 + w;        // wave's sample
  const float4 xv = *reinterpret_cast<const float4*>(
      x + (size_t)b * NFEAS + base + (lane << 2));

  if (tid < 256) {                 // s = tid>>5 (sample), ch = tid&31
    s2l[tid] = s2m[(size_t)c * (BATCH * HID) +
                   (size_t)(bg * 8 + (tid >> 5)) * HID + (hq << 5) + (tid & 31)];
  }
  if (tid < 32) cvl[tid] = Cv[(hq << 5) + tid];

  { // stage W slice [32h x 256f], coalesced along h, XOR-swizzled columns
    const int hb = tid & 7, f0 = tid >> 3;          // f0: 0..63
    const float* wp = W + (size_t)(base + f0) * HID + (hq << 5) + (hb << 2);
    const int colw = f0 ^ ((hb & 3) << 3);
    #pragma unroll
    for (int k = 0; k < 4; ++k) {
      const float4 v = *reinterpret_cast<const float4*>(wp + (size_t)(k << 6) * HID);
      float* q = &wt[((hb << 2) << 8) + colw + (k << 6)];
      q[0] = v.x; q[256] = v.y; q[512] = v.z; q[768] = v.w;
    }
  }
  __syncthreads();

  const float xm0 = xv.x > 0.f ? 1.f : 0.f;
  const float xm1 = xv.y > 0.f ? 1.f : 0.f;
  const float xm2 = xv.z > 0.f ? 1.f : 0.f;
  const float xm3 = xv.w > 0.f ? 1.f : 0.f;
  const bool qk = (c == 0) && (lane == 0);

  float z0 = 0.f, z1 = 0.f, z2 = 0.f, z3 = 0.f;
  const float* s2p = &s2l[w << 5];

  #pragma unroll
  for (int cg = 0; cg < 8; ++cg) {           // chains ch = 4*cg .. 4*cg+3
    const int colx = (lane << 2) ^ ((cg & 3) << 3);
    const int rb = (cg << 2) * 256 + colx;
    const float4 wv0 = *reinterpret_cast<const float4*>(&wt[rb]);
    const float4 wv1 = *reinterpret_cast<const float4*>(&wt[rb + 256]);
    const float4 wv2 = *reinterpret_cast<const float4*>(&wt[rb + 512]);
    const float4 wv3 = *reinterpret_cast<const float4*>(&wt[rb + 768]);

    const float m00 = wv0.x * xm0, m01 = wv0.y * xm1, m02 = wv0.z * xm2;
    const float m10 = wv1.x * xm0, m11 = wv1.y * xm1, m12 = wv1.z * xm2;
    const float m20 = wv2.x * xm0, m21 = wv2.y * xm1, m22 = wv2.z * xm2;
    const float m30 = wv3.x * xm0, m31 = wv3.y * xm1, m32 = wv3.z * xm2;

    const float ps0 = (m00 + m01) + (m02 + wv0.w * xm3);
    const float ps1 = (m10 + m11) + (m12 + wv1.w * xm3);
    const float ps2 = (m20 + m21) + (m22 + wv2.w * xm3);
    const float ps3 = (m30 + m31) + (m32 + wv3.w * xm3);

    float r0 = ps0, r1 = ps1, r2 = ps2, r3 = ps3;
    scan64_x4(r0, r1, r2, r3);

#define CHAIN(J, wvJ, rJ, psJ, mJ0, mJ1, mJ2)                                               \
    {                                                                                        \
      const int ch = (cg << 2) + J;                                                          \
      const float smv = s2p[ch];                                                             \
      const float e0 = rJ - psJ;                                                             \
      const float e1 = e0 + mJ0;                                                             \
      const float e2 = e1 + mJ1;                                                             \
      const float e3 = e2 + mJ2;                                                             \
      float g0 = __builtin_amdgcn_rcpf(1.f + __builtin_amdgcn_exp2f(__builtin_fmaf(e0, -L2E, smv))); \
      const float g1 = __builtin_amdgcn_rcpf(1.f + __builtin_amdgcn_exp2f(__builtin_fmaf(e1, -L2E, smv))); \
      const float g2 = __builtin_amdgcn_rcpf(1.f + __builtin_amdgcn_exp2f(__builtin_fmaf(e2, -L2E, smv))); \
      const float g3 = __builtin_amdgcn_rcpf(1.f + __builtin_amdgcn_exp2f(__builtin_fmaf(e3, -L2E, smv))); \
      if (qk) g0 = cvl[ch];                    /* raw C at global feature 0 */               \
      z0 = __builtin_fmaf(g0, wvJ.x, z0);                                                    \
      z1 = __builtin_fmaf(g1, wvJ.y, z1);                                                    \
      z2 = __builtin_fmaf(g2, wvJ.z, z2);                                                    \
      z3 = __builtin_fmaf(g3, wvJ.w, z3);                                                    \
    }
    CHAIN(0, wv0, r0, ps0, m00, m01, m02)
    CHAIN(1, wv1, r1, ps1, m10, m11, m12)
    CHAIN(2, wv2, r2, ps2, m20, m21, m22)
    CHAIN(3, wv3, r3, ps3, m30, m31, m32)
#undef CHAIN
  }

  f32x4 zv; zv.x = z0; zv.y = z1; zv.z = z2; zv.w = z3;
  __builtin_nontemporal_store(zv, reinterpret_cast<f32x4*>(
      &zpart[((size_t)hq * BATCH + b) * NFEAS + base + (lane << 2)]));
}

// ---------------------------------------------------------------------------
// Phase D: per-(sample, f-quarter) BCE over z = sum_hq zpart + B.
// Grid (BATCH, 4) = 512 blocks; zpart read non-temporally (read-once).
// ---------------------------------------------------------------------------
__global__ __launch_bounds__(256) void bce_kernel(
    const float* __restrict__ x, const float* __restrict__ Bv,
    const float* __restrict__ zpart, float* __restrict__ lossb)
{
  __shared__ float sm[256];
  const int b = blockIdx.x, q = blockIdx.y, t = threadIdx.x;
  const int fb = (q << 10) + (t << 2);          // 4 consecutive features
  const size_t Q = (size_t)BATCH * NFEAS;
  const size_t o = (size_t)b * NFEAS + fb;

  f32x4 zt = __builtin_nontemporal_load(
      reinterpret_cast<const f32x4*>(&zpart[o]));
  #pragma unroll
  for (int s = 1; s < 4; ++s) {
    const f32x4 v = __builtin_nontemporal_load(
        reinterpret_cast<const f32x4*>(&zpart[(size_t)s * Q + o]));
    zt.x += v.x; zt.y += v.y; zt.z += v.z; zt.w += v.w;
  }
  const float4 bv = *reinterpret_cast<const float4*>(Bv + fb);
  zt.x += bv.x; zt.y += bv.y; zt.z += bv.z; zt.w += bv.w;
  const float4 xv = *reinterpret_cast<const float4*>(&x[o]);

#define BCE(zv, xvv)                                                      \
  (fmaxf(zv, 0.f) - ((xvv) > 0.f ? (zv) : 0.f) +                          \
   LN2 * __builtin_amdgcn_logf(1.f + __builtin_amdgcn_exp2f(-L2E * __builtin_fabsf(zv))))
  const float li = (BCE(zt.x, xv.x) + BCE(zt.y, xv.y)) +
                   (BCE(zt.z, xv.z) + BCE(zt.w, xv.w));
#undef BCE

  sm[t] = li;
  __syncthreads();
  for (int s = 128; s > 0; s >>= 1) {
    if (t < s) sm[t] += sm[t + s];
    __syncthreads();
  }
  if (t == 0) lossb[b * 4 + q] = sm[0];
}

// ---------------------------------------------------------------------------
// Finalize: mean over the 512 partial losses.
// ---------------------------------------------------------------------------
__global__ __launch_bounds__(256) void finalize_kernel(
    const float* __restrict__ lossb, float* __restrict__ out)
{
  __shared__ float sm[256];
  const int t = threadIdx.x;
  sm[t] = lossb[t] + lossb[t + 256];
  __syncthreads();
  for (int s = 128; s > 0; s >>= 1) {
    if (t < s) sm[t] += sm[t + s];
    __syncthreads();
  }
  if (t == 0) out[0] = sm[0] * (1.f / BATCH);
}

// ---------------------------------------------------------------------------
extern "C" void kernel_launch(void* const* d_in, const int* in_sizes, int n_in,
                              void* d_out, int out_size, void* d_ws, size_t ws_size,
                              hipStream_t stream)
{
  const float* x  = (const float*)d_in[0];  // [BATCH, NFEAS]
  const float* Cv = (const float*)d_in[1];  // [1, HID]
  const float* W  = (const float*)d_in[2];  // [NFEAS, HID]
  const float* Bv = (const float*)d_in[3];  // [NFEAS]
  float* out = (float*)d_out;

  float* T     = (float*)d_ws;                         // [B][HID][64]   4 MB
  float* s2m   = T     + (size_t)BATCH * HID * NSUB;   // [16][B][HID]   1 MB
  float* zpart = s2m   + (size_t)NCH * BATCH * HID;    // [4][B][NFEAS]  8 MB
  float* lossb = zpart + (size_t)4 * BATCH * NFEAS;    // [B*4]

  chunk_sums_kernel<<<dim3(NSUB, BATCH / 8), 128, 0, stream>>>(x, W, T);
  prefix_s2m_kernel<<<dim3(BATCH * HID / 4), 256, 0, stream>>>(T, Cv, s2m);
  zpart_kernel<<<dim3(BATCH / 8, NCH, 4), 512, 0, stream>>>(x, W, Cv, s2m, zpart);
  bce_kernel<<<dim3(BATCH, 4), 256, 0, stream>>>(x, Bv, zpart, lossb);
  finalize_kernel<<<1, 256, 0, stream>>>(lossb, out);
}